// Round 2
// baseline (389.618 us; speedup 1.0000x reference)
//
#include <hip/hip_runtime.h>
#include <stdint.h>

typedef __bf16 bf16;
typedef __bf16 bf16x4 __attribute__((ext_vector_type(4)));
typedef __bf16 bf16x8 __attribute__((ext_vector_type(8)));
typedef float f32x4 __attribute__((ext_vector_type(4)));

#define AS1 __attribute__((address_space(1)))
#define AS3 __attribute__((address_space(3)))

__device__ __forceinline__ void async16(void* lds, const void* g) {
    __builtin_amdgcn_global_load_lds((AS1 void*)g, (AS3 void*)lds, 16, 0, 0);
}

// ---------------------------------------------------------------------------
// Prep: z<3 -> fp32->bf16 convert of X tensors; z==3 -> 4 weight transposes.
// ---------------------------------------------------------------------------
__global__ __launch_bounds__(256) void prep(
    const float* __restrict__ x0, const float* __restrict__ x1,
    const float* __restrict__ x2,
    bf16* __restrict__ y0, bf16* __restrict__ y1, bf16* __restrict__ y2,
    const float* __restrict__ s0, const float* __restrict__ s1,
    const float* __restrict__ s2, const float* __restrict__ s3,
    bf16* __restrict__ d0, bf16* __restrict__ d1,
    bf16* __restrict__ d2, bf16* __restrict__ d3) {
    const int z = blockIdx.z;
    const int t = threadIdx.x;
    if (z < 3) {
        const float* x = z == 0 ? x0 : z == 1 ? x1 : x2;
        bf16* y = z == 0 ? y0 : z == 1 ? y1 : y2;
        int i = (blockIdx.x * 256 + t) * 8;
        f32x4 a = *(const f32x4*)(x + i);
        f32x4 b = *(const f32x4*)(x + i + 4);
        bf16x8 o;
#pragma unroll
        for (int j = 0; j < 4; ++j) { o[j] = (bf16)a[j]; o[4 + j] = (bf16)b[j]; }
        *(bf16x8*)(y + i) = o;
        return;
    }
    const int bx = blockIdx.x;
    if (bx >= 1024) return;
    const int wsel = bx >> 8, tile = bx & 255;
    const float* W = wsel == 0 ? s0 : wsel == 1 ? s1 : wsel == 2 ? s2 : s3;
    bf16* Wt = wsel == 0 ? d0 : wsel == 1 ? d1 : wsel == 2 ? d2 : d3;
    const int k0 = (tile >> 4) * 64, n0 = (tile & 15) * 64;
    __shared__ float Ts[64 * 65];
    const int c = t & 63, r0 = t >> 6;
#pragma unroll
    for (int i = 0; i < 16; ++i) {
        int r = r0 + i * 4;
        Ts[r * 65 + c] = W[(size_t)(k0 + r) * 1024 + n0 + c];
    }
    __syncthreads();
#pragma unroll
    for (int i = 0; i < 16; ++i) {
        int r = r0 + i * 4;
        Wt[(size_t)(n0 + r) * 1024 + k0 + c] = (bf16)Ts[c * 65 + r];
    }
}

// ---------------------------------------------------------------------------
// 256-row pipelined GEMM body. BM=256, BN=NREP*64 (256 or 128), BK=64, K=1024.
// 8 waves (2 M x 4 N), per-wave output 128 x NREP*16. Double-buffered LDS,
// counted vmcnt (issue prefetch for tile t+1 early, wait only for tile t),
// raw s_barrier (no full drain), 4 MFMA phases interleaved with ds_reads and
// prefetch issues, setprio around MFMA clusters. Xor-swizzled LDS rows.
// C[M][N] = A[M][K] * Bt[N][K]^T * scale.
// ---------------------------------------------------------------------------
template <int NREP, typename OutT>
__device__ __forceinline__ void gemm256_body(
    const bf16* __restrict__ A, const bf16* __restrict__ Bt,
    OutT* __restrict__ C, int N, float scale, int m0, int n0,
    bf16* As0, bf16* As1, bf16* Bs0, bf16* Bs1) {
    const int t = threadIdx.x;
    const int lane = t & 63;
    const int w = t >> 6;
    const int l15 = lane & 15;
    const int quad = lane >> 4;
    const int wm = w >> 2, wn = w & 3;      // 2 x 4 wave grid
    constexpr int K = 1024;

    f32x4 acc[8][NREP];
#pragma unroll
    for (int i = 0; i < 8; ++i)
#pragma unroll
        for (int j = 0; j < NREP; ++j) acc[i][j] = (f32x4){0.f, 0.f, 0.f, 0.f};

    // staging pointers: chunk c = j*512 + t -> lds row c>>3, phys group c&7,
    // global k-group g = (c&7) ^ (row&7)  (xor swizzle)
    const bf16* pA[4];
    const bf16* pB[NREP];
#pragma unroll
    for (int j = 0; j < 4; ++j) {
        int c = j * 512 + t, row = c >> 3, g = (c & 7) ^ (row & 7);
        pA[j] = A + (size_t)(m0 + row) * K + g * 8;
    }
#pragma unroll
    for (int j = 0; j < NREP; ++j) {
        int c = j * 512 + t, row = c >> 3, g = (c & 7) ^ (row & 7);
        pB[j] = Bt + (size_t)(n0 + row) * K + g * 8;
    }
    bf16* AsB[2] = {As0, As1};
    bf16* BsB[2] = {Bs0, Bs1};

    // prologue: stage tile 0 into buffer 0 (A: 4 chunks, B: NREP chunks)
#pragma unroll
    for (int j = 0; j < 4; ++j) {
        async16(As0 + (j * 512 + w * 64) * 8, pA[j]); pA[j] += 64;
    }
#pragma unroll
    for (int j = 0; j < NREP; ++j) {
        async16(Bs0 + (j * 512 + w * 64) * 8, pB[j]); pB[j] += 64;
    }

    for (int tt = 0; tt < 16; ++tt) {
        const int cb = tt & 1, ob = cb ^ 1;
        const bf16* Acur = AsB[cb];
        const bf16* Bcur = BsB[cb];
        bf16* Anxt = AsB[ob];
        bf16* Bnxt = BsB[ob];
        const bool pf = tt < 15;

        // issue first 4 prefetch loads for tile t+1, then wait for tile t only
        if (pf) {
            async16(Anxt + (0 * 512 + w * 64) * 8, pA[0]); pA[0] += 64;
            async16(Anxt + (1 * 512 + w * 64) * 8, pA[1]); pA[1] += 64;
            async16(Bnxt + (0 * 512 + w * 64) * 8, pB[0]); pB[0] += 64;
            async16(Bnxt + (1 * 512 + w * 64) * 8, pB[1]); pB[1] += 64;
            asm volatile("s_waitcnt vmcnt(4)" ::: "memory");
        } else {
            asm volatile("s_waitcnt vmcnt(0)" ::: "memory");
        }
        __builtin_amdgcn_s_barrier();

        bf16x8 aF[8];
        bf16x8 bF[NREP * 2];

        // --- phase 1: read A-lo (mi 0..3) + B n0-1; MFMA quadrant 1 ---
#pragma unroll
        for (int mi = 0; mi < 4; ++mi)
#pragma unroll
            for (int kk = 0; kk < 2; ++kk) {
                int r = wm * 128 + mi * 16 + l15;
                aF[mi * 2 + kk] =
                    *(const bf16x8*)&Acur[r * 64 + (((kk * 4 + quad) ^ (r & 7)) * 8)];
            }
#pragma unroll
        for (int ni = 0; ni < 2; ++ni)
#pragma unroll
            for (int kk = 0; kk < 2; ++kk) {
                int r = wn * (NREP * 16) + ni * 16 + l15;
                bF[ni * 2 + kk] =
                    *(const bf16x8*)&Bcur[r * 64 + (((kk * 4 + quad) ^ (r & 7)) * 8)];
            }
        __builtin_amdgcn_s_setprio(1);
#pragma unroll
        for (int mi = 0; mi < 4; ++mi)
#pragma unroll
            for (int ni = 0; ni < 2; ++ni)
#pragma unroll
                for (int kk = 0; kk < 2; ++kk)
                    acc[mi][ni] = __builtin_amdgcn_mfma_f32_16x16x32_bf16(
                        aF[mi * 2 + kk], bF[ni * 2 + kk], acc[mi][ni], 0, 0, 0);
        __builtin_amdgcn_s_setprio(0);

        if constexpr (NREP == 4) {
            // --- phase 2: read B n2-3; issue A-hi prefetch; MFMA quadrant 2 ---
#pragma unroll
            for (int ni = 2; ni < 4; ++ni)
#pragma unroll
                for (int kk = 0; kk < 2; ++kk) {
                    int r = wn * 64 + ni * 16 + l15;
                    bF[ni * 2 + kk] =
                        *(const bf16x8*)&Bcur[r * 64 + (((kk * 4 + quad) ^ (r & 7)) * 8)];
                }
            if (pf) {
                async16(Anxt + (2 * 512 + w * 64) * 8, pA[2]); pA[2] += 64;
                async16(Anxt + (3 * 512 + w * 64) * 8, pA[3]); pA[3] += 64;
            }
            __builtin_amdgcn_s_setprio(1);
#pragma unroll
            for (int mi = 0; mi < 4; ++mi)
#pragma unroll
                for (int ni = 2; ni < 4; ++ni)
#pragma unroll
                    for (int kk = 0; kk < 2; ++kk)
                        acc[mi][ni] = __builtin_amdgcn_mfma_f32_16x16x32_bf16(
                            aF[mi * 2 + kk], bF[ni * 2 + kk], acc[mi][ni], 0, 0, 0);
            __builtin_amdgcn_s_setprio(0);

            // --- phase 3: read A-hi (mi 4..7); issue B-hi prefetch; MFMA q3 ---
#pragma unroll
            for (int mi = 0; mi < 4; ++mi)
#pragma unroll
                for (int kk = 0; kk < 2; ++kk) {
                    int r = wm * 128 + (mi + 4) * 16 + l15;
                    aF[mi * 2 + kk] =
                        *(const bf16x8*)&Acur[r * 64 + (((kk * 4 + quad) ^ (r & 7)) * 8)];
                }
            if (pf) {
                async16(Bnxt + (2 * 512 + w * 64) * 8, pB[2]); pB[2] += 64;
                async16(Bnxt + (3 * 512 + w * 64) * 8, pB[3]); pB[3] += 64;
            }
            __builtin_amdgcn_s_setprio(1);
#pragma unroll
            for (int mi = 4; mi < 8; ++mi)
#pragma unroll
                for (int ni = 2; ni < 4; ++ni)
#pragma unroll
                    for (int kk = 0; kk < 2; ++kk)
                        acc[mi][ni] = __builtin_amdgcn_mfma_f32_16x16x32_bf16(
                            aF[(mi & 3) * 2 + kk], bF[ni * 2 + kk], acc[mi][ni], 0, 0, 0);
            __builtin_amdgcn_s_setprio(0);

            // --- phase 4: MFMA quadrant 4 (no reads) ---
            __builtin_amdgcn_s_setprio(1);
#pragma unroll
            for (int mi = 4; mi < 8; ++mi)
#pragma unroll
                for (int ni = 0; ni < 2; ++ni)
#pragma unroll
                    for (int kk = 0; kk < 2; ++kk)
                        acc[mi][ni] = __builtin_amdgcn_mfma_f32_16x16x32_bf16(
                            aF[(mi & 3) * 2 + kk], bF[ni * 2 + kk], acc[mi][ni], 0, 0, 0);
            __builtin_amdgcn_s_setprio(0);
        } else {
            // --- phase 2 (NREP==2): read A-hi; issue A-hi prefetch; MFMA q2 ---
#pragma unroll
            for (int mi = 0; mi < 4; ++mi)
#pragma unroll
                for (int kk = 0; kk < 2; ++kk) {
                    int r = wm * 128 + (mi + 4) * 16 + l15;
                    aF[mi * 2 + kk] =
                        *(const bf16x8*)&Acur[r * 64 + (((kk * 4 + quad) ^ (r & 7)) * 8)];
                }
            if (pf) {
                async16(Anxt + (2 * 512 + w * 64) * 8, pA[2]); pA[2] += 64;
                async16(Anxt + (3 * 512 + w * 64) * 8, pA[3]); pA[3] += 64;
            }
            __builtin_amdgcn_s_setprio(1);
#pragma unroll
            for (int mi = 4; mi < 8; ++mi)
#pragma unroll
                for (int ni = 0; ni < 2; ++ni)
#pragma unroll
                    for (int kk = 0; kk < 2; ++kk)
                        acc[mi][ni] = __builtin_amdgcn_mfma_f32_16x16x32_bf16(
                            aF[(mi & 3) * 2 + kk], bF[ni * 2 + kk], acc[mi][ni], 0, 0, 0);
            __builtin_amdgcn_s_setprio(0);
        }

        // all ds_reads must be complete before any wave re-stages this buffer
        asm volatile("s_waitcnt lgkmcnt(0)" ::: "memory");
        __builtin_amdgcn_s_barrier();
    }

    // epilogue
#pragma unroll
    for (int mi = 0; mi < 8; ++mi)
#pragma unroll
        for (int ni = 0; ni < NREP; ++ni)
#pragma unroll
            for (int r = 0; r < 4; ++r) {
                int row = m0 + wm * 128 + mi * 16 + quad * 4 + r;
                int col = n0 + wn * (NREP * 16) + ni * 16 + l15;
                C[(size_t)row * N + col] = (OutT)(acc[mi][ni][r] * scale);
            }
}

// Batched Q/K/V projection. z=0: Qb=Xq*Wq^T*(0.125*log2e); z=1: Kb; z=2: VtG.
// 128 blocks/slice (32 big-tiles x 4 small-tiles of 256). Decode: each XCD
// (bid&7 under round-robin) gets ONE small-tile B-panel (L2-resident) and a
// set of big-tile A-panels.
__global__ __launch_bounds__(512, 2) void gemm_qkv(
    const bf16* __restrict__ Xq, const bf16* __restrict__ Xk, const bf16* __restrict__ Xv,
    const bf16* __restrict__ Wqt, const bf16* __restrict__ Wkt, const bf16* __restrict__ Wvt,
    bf16* __restrict__ Qb, bf16* __restrict__ Kb, bf16* __restrict__ VtG) {
    __shared__ __align__(16) bf16 As[2][256 * 64];
    __shared__ __align__(16) bf16 Bs[2][256 * 64];
    const int z = blockIdx.z;
    const int x = blockIdx.x;
    const int sml = (x & 7) >> 1;               // 0..3
    const int big = (x >> 3) * 2 + (x & 1);     // 0..31
    const bf16* A; const bf16* Bt; bf16* C; int N; float scale; int m0, n0;
    if (z == 0) { A = Xq; Bt = Wqt; C = Qb; N = 1024; scale = 0.18033688011112042f;
                  m0 = big * 256; n0 = sml * 256; }   // 0.125 * log2(e)
    else if (z == 1) { A = Xk; Bt = Wkt; C = Kb; N = 1024; scale = 1.0f;
                  m0 = big * 256; n0 = sml * 256; }
    else { A = Wvt; Bt = Xv; C = VtG; N = 8192; scale = 1.0f;
                  m0 = sml * 256; n0 = big * 256; }
    gemm256_body<4, bf16>(A, Bt, C, N, scale, m0, n0, As[0], As[1], Bs[0], Bs[1]);
}

// Output projection: out[8192][1024] fp32 = Cb * Wot^T. BN=128 variant:
// 256 blocks (32 m x 8 n) = perfectly balanced 1 block/CU; bn = x&7 pins one
// 256KB B-panel per XCD.
__global__ __launch_bounds__(512, 2) void gemm_out(const bf16* __restrict__ A,
                                                   const bf16* __restrict__ Bt,
                                                   float* __restrict__ C) {
    __shared__ __align__(16) bf16 As[2][256 * 64];
    __shared__ __align__(16) bf16 Bs[2][128 * 64];
    const int x = blockIdx.x;
    const int bm = x >> 3, bn = x & 7;
    gemm256_body<2, float>(A, Bt, C, 1024, 1.0f, bm * 256, bn * 128,
                           As[0], As[1], Bs[0], Bs[1]);
}

// ---------------------------------------------------------------------------
// Flash attention, S^T formulation, no online max (|s*log2e|<=10.7: fp32-safe).
// 8 waves / 256 q-rows per block; 512 blocks = exactly 2 resident per CU
// (LDS exactly 64 KB) -> 16 waves/CU. One barrier per iter, K/V double-
// buffered, prefetch for tile i+1 issued right after the barrier.
// ---------------------------------------------------------------------------
__global__ __launch_bounds__(512) void attn_fa(const bf16* __restrict__ Q,
                                               const bf16* __restrict__ K,
                                               const bf16* __restrict__ Vt,
                                               bf16* __restrict__ O) {
    __shared__ __align__(16) bf16 Ks[2][64 * 64];   // swizzled [t][dh]
    __shared__ __align__(16) bf16 Vs[2][64 * 64];   // swizzled [dh][t]
    __shared__ __align__(16) bf16 Pt[8][32 * 64];   // per-wave P^T, xor-swizzled

    const int t = threadIdx.x;
    const int lane = t & 63;
    const int w = t >> 6;
    const int l15 = lane & 15;
    const int quad = lane >> 4;
    const int q7 = l15 & 7;

    const int bid = blockIdx.x;
    const int bh = (bid & 7) * 8 + ((bid >> 3) & 7);
    const int q0 = (bid >> 6) * 256;
    const int b = bh >> 4, h = bh & 15;
    const size_t baseQ = (size_t)b * 2048 * 1024 + (size_t)h * 64;

    const int r0s = t >> 3, g0s = (t & 7) ^ (r0s & 7);
    const bf16* gK0 = K + baseQ + (size_t)r0s * 1024 + g0s * 8;
    const bf16* gV0 = Vt + (size_t)(h * 64 + r0s) * 8192 + (size_t)b * 2048 + g0s * 8;

    bf16x8 qf[2][2];
#pragma unroll
    for (int mi = 0; mi < 2; ++mi)
#pragma unroll
        for (int kk = 0; kk < 2; ++kk)
            qf[mi][kk] = *(const bf16x8*)(Q + baseQ +
                (size_t)(q0 + w * 32 + mi * 16 + l15) * 1024 + kk * 32 + quad * 8);

    f32x4 accO[4][2];
    float l_part[2] = {0.f, 0.f};
#pragma unroll
    for (int nd = 0; nd < 4; ++nd)
#pragma unroll
        for (int mi = 0; mi < 2; ++mi) accO[nd][mi] = (f32x4){0.f, 0.f, 0.f, 0.f};

    auto swz = [&](int r, int g) { return (r * 8 + (g ^ (r & 7))) * 8; };
    auto stage = [&](int t0, int bi) {
        async16((bf16*)Ks[bi] + w * 512, gK0 + (size_t)t0 * 1024);
        async16((bf16*)Vs[bi] + w * 512, gV0 + t0);
    };

    stage(0, 0);

    for (int it = 0; it < 32; ++it) {
        __syncthreads();
        if (it + 1 < 32) stage((it + 1) * 64, (it + 1) & 1);
        const bf16* Kb = Ks[it & 1];
        const bf16* Vb = Vs[it & 1];

        f32x4 accS[4][2];
#pragma unroll
        for (int nt = 0; nt < 4; ++nt)
#pragma unroll
            for (int mi = 0; mi < 2; ++mi) accS[nt][mi] = (f32x4){0.f, 0.f, 0.f, 0.f};
#pragma unroll
        for (int kk = 0; kk < 2; ++kk) {
            bf16x8 kf[4];
#pragma unroll
            for (int nt = 0; nt < 4; ++nt)
                kf[nt] = *(const bf16x8*)&Kb[swz(nt * 16 + l15, kk * 4 + quad)];
            __builtin_amdgcn_s_setprio(1);
#pragma unroll
            for (int nt = 0; nt < 4; ++nt)
#pragma unroll
                for (int mi = 0; mi < 2; ++mi)
                    accS[nt][mi] = __builtin_amdgcn_mfma_f32_16x16x32_bf16(
                        kf[nt], qf[mi][kk], accS[nt][mi], 0, 0, 0);
            __builtin_amdgcn_s_setprio(0);
        }

        bf16* Pp = &Pt[w][0];
#pragma unroll
        for (int mi = 0; mi < 2; ++mi) {
            const int qbase = (mi * 16 + l15) * 64;
            float rs = 0.f;
#pragma unroll
            for (int nt = 0; nt < 4; ++nt) {
                bf16x4 pk;
#pragma unroll
                for (int r = 0; r < 4; ++r) {
                    float p = __builtin_amdgcn_exp2f(accS[nt][mi][r]);
                    rs += p;
                    pk[r] = (bf16)p;
                }
                *(bf16x4*)&Pp[qbase + (((nt * 2 + (quad >> 1)) ^ q7) * 8) +
                              (quad & 1) * 4] = pk;
            }
            l_part[mi] += rs;
        }

#pragma unroll
        for (int kk = 0; kk < 2; ++kk) {
            bf16x8 vf[4], pf[2];
#pragma unroll
            for (int nd = 0; nd < 4; ++nd)
                vf[nd] = *(const bf16x8*)&Vb[swz(nd * 16 + l15, kk * 4 + quad)];
#pragma unroll
            for (int mi = 0; mi < 2; ++mi)
                pf[mi] = *(const bf16x8*)&Pp[(mi * 16 + l15) * 64 +
                                             (((kk * 4 + quad) ^ q7) * 8)];
            __builtin_amdgcn_s_setprio(1);
#pragma unroll
            for (int nd = 0; nd < 4; ++nd)
#pragma unroll
                for (int mi = 0; mi < 2; ++mi)
                    accO[nd][mi] = __builtin_amdgcn_mfma_f32_16x16x32_bf16(
                        vf[nd], pf[mi], accO[nd][mi], 0, 0, 0);
            __builtin_amdgcn_s_setprio(0);
        }
    }

    float inv[2];
#pragma unroll
    for (int mi = 0; mi < 2; ++mi) {
        float l = l_part[mi];
        l += __shfl_xor(l, 16);
        l += __shfl_xor(l, 32);
        inv[mi] = 1.0f / l;
    }

#pragma unroll
    for (int mi = 0; mi < 2; ++mi) {
        size_t rowoff = baseQ + (size_t)(q0 + w * 32 + mi * 16 + l15) * 1024;
#pragma unroll
        for (int nd = 0; nd < 4; ++nd) {
            bf16x4 o;
#pragma unroll
            for (int r = 0; r < 4; ++r) o[r] = (bf16)(accO[nd][mi][r] * inv[mi]);
            *(bf16x4*)&O[rowoff + nd * 16 + quad * 4] = o;
        }
    }
}

// ---------------------------------------------------------------------------
extern "C" void kernel_launch(void* const* d_in, const int* in_sizes, int n_in,
                              void* d_out, int out_size, void* d_ws, size_t ws_size,
                              hipStream_t stream) {
    const float* qin = (const float*)d_in[0];
    const float* kin = (const float*)d_in[1];
    const float* vin = (const float*)d_in[2];
    const float* Wq = (const float*)d_in[3];
    const float* Wk = (const float*)d_in[4];
    const float* Wv = (const float*)d_in[5];
    const float* Wo = (const float*)d_in[6];
    float* out = (float*)d_out;

    char* ws = (char*)d_ws;
    bf16* Xq  = (bf16*)(ws);                       // 16 MB each
    bf16* Xk  = (bf16*)(ws + ((size_t)16 << 20));
    bf16* Xv  = (bf16*)(ws + ((size_t)32 << 20));
    bf16* Qb  = (bf16*)(ws + ((size_t)48 << 20));
    bf16* Kb  = (bf16*)(ws + ((size_t)64 << 20));
    bf16* VtG = (bf16*)(ws + ((size_t)80 << 20));  // [1024][8192] = V^T
    bf16* Cb  = (bf16*)(ws);                       // alias Xq (dead after gemm_qkv)
    bf16* Wqt = (bf16*)(ws + ((size_t)96 << 20));
    bf16* Wkt = Wqt + 1024 * 1024;
    bf16* Wvt = Wkt + 1024 * 1024;
    bf16* Wot = Wvt + 1024 * 1024;

    prep<<<dim3(4096, 1, 4), 256, 0, stream>>>(qin, kin, vin, Xq, Xk, Xv,
                                               Wq, Wk, Wv, Wo, Wqt, Wkt, Wvt, Wot);
    gemm_qkv<<<dim3(128, 1, 3), 512, 0, stream>>>(Xq, Xk, Xv, Wqt, Wkt, Wvt,
                                                  Qb, Kb, VtG);
    attn_fa<<<dim3(512), 512, 0, stream>>>(Qb, Kb, VtG, Cb);
    gemm_out<<<dim3(256), 512, 0, stream>>>(Cb, Wot, out);
}

// Round 3
// 351.616 us; speedup vs baseline: 1.1081x; 1.1081x over previous
//
#include <hip/hip_runtime.h>
#include <stdint.h>

typedef __bf16 bf16;
typedef __bf16 bf16x4 __attribute__((ext_vector_type(4)));
typedef __bf16 bf16x8 __attribute__((ext_vector_type(8)));
typedef float f32x4 __attribute__((ext_vector_type(4)));

#define AS1 __attribute__((address_space(1)))
#define AS3 __attribute__((address_space(3)))

__device__ __forceinline__ void async16(void* lds, const void* g) {
    __builtin_amdgcn_global_load_lds((AS1 void*)g, (AS3 void*)lds, 16, 0, 0);
}

// ---------------------------------------------------------------------------
// Prep: weight transposes only (X fp32->bf16 convert is fused into gemm_qkv).
// 1024 blocks: 4 weights x 256 64x64 tiles.
// ---------------------------------------------------------------------------
__global__ __launch_bounds__(256) void prep(
    const float* __restrict__ s0, const float* __restrict__ s1,
    const float* __restrict__ s2, const float* __restrict__ s3,
    bf16* __restrict__ d0, bf16* __restrict__ d1,
    bf16* __restrict__ d2, bf16* __restrict__ d3) {
    const int bx = blockIdx.x;
    const int t = threadIdx.x;
    const int wsel = bx >> 8, tile = bx & 255;
    const float* W = wsel == 0 ? s0 : wsel == 1 ? s1 : wsel == 2 ? s2 : s3;
    bf16* Wt = wsel == 0 ? d0 : wsel == 1 ? d1 : wsel == 2 ? d2 : d3;
    const int k0 = (tile >> 4) * 64, n0 = (tile & 15) * 64;
    __shared__ float Ts[64 * 65];
    const int c = t & 63, r0 = t >> 6;
#pragma unroll
    for (int i = 0; i < 16; ++i) {
        int r = r0 + i * 4;
        Ts[r * 65 + c] = W[(size_t)(k0 + r) * 1024 + n0 + c];
    }
    __syncthreads();
#pragma unroll
    for (int i = 0; i < 16; ++i) {
        int r = r0 + i * 4;
        Wt[(size_t)(n0 + r) * 1024 + k0 + c] = (bf16)Ts[c * 65 + r];
    }
}

// ---------------------------------------------------------------------------
// 128x128 GEMM body, BK=64, xor-swizzled LDS rows (conflict-free b128 reads).
// C[M][N] = A[M][K]*Bt[N][K]^T * scale. 16 K-iterations at K=1024.
// AF32/BF32: that operand is fp32 in global; staged via reg (8x f32x4 load ->
// convert -> 4x ds_write_b128, same swizzled layout). The fp32 prefetch for
// tile t+1 issues AFTER barrier-2, overlapping the compute phase (T14); the
// raw barrier-1 (no vmcnt drain) lets it stay in flight across iterations.
// bf16 operands stage via global_load_lds (width 16) as before.
// ---------------------------------------------------------------------------
template <int AF32, int BF32, typename OutT>
__device__ __forceinline__ void gemm_body(const void* Ap, const void* Bp,
                                          OutT* __restrict__ C,
                                          int N, int K, float scale,
                                          int m0, int n0,
                                          bf16* As, bf16* Bs) {
    const int t = threadIdx.x;
    const int lane = t & 63;
    const int w = t >> 6;
    const int l15 = lane & 15;
    const int quad = lane >> 4;
    const int wm = w >> 1, wn = w & 1;

    f32x4 acc[4][4];
#pragma unroll
    for (int i = 0; i < 4; ++i)
#pragma unroll
        for (int j = 0; j < 4; ++j) acc[i][j] = (f32x4){0.f, 0.f, 0.f, 0.f};

    // staging: 1024 16B-chunks (bf16-space) per matrix per iter; thread t ->
    // chunks t+j*256. chunk c -> LDS byte 16c; logical row=c>>3, phys col
    // group c&7, global col group g = (c&7) ^ (row&7)  (xor swizzle).
    int crow[4], cg[4];
#pragma unroll
    for (int j = 0; j < 4; ++j) {
        int c = j * 256 + t;
        crow[j] = c >> 3;
        cg[j] = (c & 7) ^ (crow[j] & 7);
    }
    const bf16* a16[4]; const float* a32[4];
    const bf16* b16[4]; const float* b32[4];
#pragma unroll
    for (int j = 0; j < 4; ++j) {
        if constexpr (AF32)
            a32[j] = (const float*)Ap + (size_t)(m0 + crow[j]) * K + cg[j] * 8;
        else
            a16[j] = (const bf16*)Ap + (size_t)(m0 + crow[j]) * K + cg[j] * 8;
        if constexpr (BF32)
            b32[j] = (const float*)Bp + (size_t)(n0 + crow[j]) * K + cg[j] * 8;
        else
            b16[j] = (const bf16*)Bp + (size_t)(n0 + crow[j]) * K + cg[j] * 8;
    }

    f32x4 ar[8], br[8];
    if constexpr (AF32) {
#pragma unroll
        for (int j = 0; j < 4; ++j) {
            ar[2 * j] = *(const f32x4*)a32[j];
            ar[2 * j + 1] = *(const f32x4*)(a32[j] + 4);
        }
    }
    if constexpr (BF32) {
#pragma unroll
        for (int j = 0; j < 4; ++j) {
            br[2 * j] = *(const f32x4*)b32[j];
            br[2 * j + 1] = *(const f32x4*)(b32[j] + 4);
        }
    }

    for (int k0 = 0; k0 < K; k0 += 64) {
        // barrier-1: all waves done consuming previous tile. Raw (no vmcnt
        // drain) so in-flight fp32 prefetch regs survive.
        __builtin_amdgcn_s_barrier();
        __builtin_amdgcn_sched_barrier(0);

        if constexpr (AF32) {
#pragma unroll
            for (int j = 0; j < 4; ++j) {
                bf16x8 cv;
#pragma unroll
                for (int r = 0; r < 4; ++r) {
                    cv[r] = (bf16)ar[2 * j][r];
                    cv[4 + r] = (bf16)ar[2 * j + 1][r];
                }
                *(bf16x8*)&As[(j * 256 + t) * 8] = cv;
            }
        } else {
#pragma unroll
            for (int j = 0; j < 4; ++j) async16(As + (j * 256 + w * 64) * 8, a16[j] + k0);
        }
        if constexpr (BF32) {
#pragma unroll
            for (int j = 0; j < 4; ++j) {
                bf16x8 cv;
#pragma unroll
                for (int r = 0; r < 4; ++r) {
                    cv[r] = (bf16)br[2 * j][r];
                    cv[4 + r] = (bf16)br[2 * j + 1][r];
                }
                *(bf16x8*)&Bs[(j * 256 + t) * 8] = cv;
            }
        } else {
#pragma unroll
            for (int j = 0; j < 4; ++j) async16(Bs + (j * 256 + w * 64) * 8, b16[j] + k0);
        }

        // barrier-2: staged data visible to all waves (async16 via vmcnt,
        // ds_write via lgkmcnt). No fp32 loads outstanding here.
        asm volatile("s_waitcnt vmcnt(0) lgkmcnt(0)" ::: "memory");
        __builtin_amdgcn_s_barrier();
        __builtin_amdgcn_sched_barrier(0);

        // fp32 prefetch for tile t+1 issues now: its ~HBM latency hides under
        // this tile's compute, consumed at next iteration's ds_write.
        const bool pf = (k0 + 64 < K);
        if (pf) {
            if constexpr (AF32) {
#pragma unroll
                for (int j = 0; j < 4; ++j) {
                    ar[2 * j] = *(const f32x4*)(a32[j] + k0 + 64);
                    ar[2 * j + 1] = *(const f32x4*)(a32[j] + k0 + 68);
                }
            }
            if constexpr (BF32) {
#pragma unroll
                for (int j = 0; j < 4; ++j) {
                    br[2 * j] = *(const f32x4*)(b32[j] + k0 + 64);
                    br[2 * j + 1] = *(const f32x4*)(b32[j] + k0 + 68);
                }
            }
        }

#pragma unroll
        for (int kk = 0; kk < 2; ++kk) {
            bf16x8 af[4], bfv[4];
#pragma unroll
            for (int mi = 0; mi < 4; ++mi) {
                int r = wm * 64 + mi * 16 + l15;
                af[mi] = *(const bf16x8*)&As[r * 64 + (((kk * 4 + quad) ^ (r & 7)) * 8)];
            }
#pragma unroll
            for (int ni = 0; ni < 4; ++ni) {
                int r = wn * 64 + ni * 16 + l15;
                bfv[ni] = *(const bf16x8*)&Bs[r * 64 + (((kk * 4 + quad) ^ (r & 7)) * 8)];
            }
#pragma unroll
            for (int mi = 0; mi < 4; ++mi)
#pragma unroll
                for (int ni = 0; ni < 4; ++ni)
                    acc[mi][ni] = __builtin_amdgcn_mfma_f32_16x16x32_bf16(
                        af[mi], bfv[ni], acc[mi][ni], 0, 0, 0);
        }
    }

#pragma unroll
    for (int mi = 0; mi < 4; ++mi)
#pragma unroll
        for (int ni = 0; ni < 4; ++ni)
#pragma unroll
            for (int r = 0; r < 4; ++r) {
                int row = m0 + wm * 64 + mi * 16 + quad * 4 + r;
                int col = n0 + wn * 64 + ni * 16 + l15;
                C[(size_t)row * N + col] = (OutT)(acc[mi][ni][r] * scale);
            }
}

// Batched Q/K/V projection, fp32 X inputs (conversion fused into staging).
// z=0: Qb = Xq*Wq^T*(0.125*log2e); z=1: Kb; z=2: VtG = (Wvt)*(Xv)^T.
// XCD grouping: blocks sharing a 128-row panel land on one XCD (bid&7).
__global__ __launch_bounds__(256) void gemm_qkv(
    const float* __restrict__ Xq, const float* __restrict__ Xk,
    const float* __restrict__ Xv,
    const bf16* __restrict__ Wqt, const bf16* __restrict__ Wkt,
    const bf16* __restrict__ Wvt,
    bf16* __restrict__ Qb, bf16* __restrict__ Kb, bf16* __restrict__ VtG) {
    __shared__ __align__(16) bf16 As[128 * 64];
    __shared__ __align__(16) bf16 Bs[128 * 64];
    const int z = blockIdx.z;
    const int blk = blockIdx.x;
    const int big = (blk & 7) * 8 + (blk >> 6);   // 0..63, grouped 8-per-XCD
    const int sml = (blk >> 3) & 7;               // 0..7
    if (z == 0)
        gemm_body<1, 0, bf16>(Xq, Wqt, Qb, 1024, 1024, 0.18033688011112042f,
                              big * 128, sml * 128, As, Bs);  // 0.125*log2(e)
    else if (z == 1)
        gemm_body<1, 0, bf16>(Xk, Wkt, Kb, 1024, 1024, 1.0f,
                              big * 128, sml * 128, As, Bs);
    else
        gemm_body<0, 1, bf16>(Wvt, Xv, VtG, 8192, 1024, 1.0f,
                              sml * 128, big * 128, As, Bs);
}

// Output projection: out[8192][1024] fp32 = Cb * Wot^T (same XCD grouping)
__global__ __launch_bounds__(256) void gemm_out(const bf16* __restrict__ A,
                                                const bf16* __restrict__ Bt,
                                                float* __restrict__ C) {
    __shared__ __align__(16) bf16 As[128 * 64];
    __shared__ __align__(16) bf16 Bs[128 * 64];
    const int blk = blockIdx.x;
    const int big = (blk & 7) * 8 + (blk >> 6);
    const int sml = (blk >> 3) & 7;
    gemm_body<0, 0, float>(A, Bt, C, 1024, 1024, 1.0f, big * 128, sml * 128,
                           As, Bs);
}

// ---------------------------------------------------------------------------
// Flash attention, S^T formulation, no online max (|s*log2e|<=10.7: fp32-safe).
// 8 waves / 256 q-rows per block; 512 blocks = exactly 2 resident per CU
// (LDS exactly 64 KB) -> 16 waves/CU. One barrier per iter, K/V double-
// buffered, prefetch for tile i+1 issued right after the barrier.
// ---------------------------------------------------------------------------
__global__ __launch_bounds__(512) void attn_fa(const bf16* __restrict__ Q,
                                               const bf16* __restrict__ K,
                                               const bf16* __restrict__ Vt,
                                               bf16* __restrict__ O) {
    __shared__ __align__(16) bf16 Ks[2][64 * 64];   // swizzled [t][dh]
    __shared__ __align__(16) bf16 Vs[2][64 * 64];   // swizzled [dh][t]
    __shared__ __align__(16) bf16 Pt[8][32 * 64];   // per-wave P^T, xor-swizzled

    const int t = threadIdx.x;
    const int lane = t & 63;
    const int w = t >> 6;
    const int l15 = lane & 15;
    const int quad = lane >> 4;
    const int q7 = l15 & 7;

    const int bid = blockIdx.x;
    const int bh = (bid & 7) * 8 + ((bid >> 3) & 7);
    const int q0 = (bid >> 6) * 256;
    const int b = bh >> 4, h = bh & 15;
    const size_t baseQ = (size_t)b * 2048 * 1024 + (size_t)h * 64;

    const int r0s = t >> 3, g0s = (t & 7) ^ (r0s & 7);
    const bf16* gK0 = K + baseQ + (size_t)r0s * 1024 + g0s * 8;
    const bf16* gV0 = Vt + (size_t)(h * 64 + r0s) * 8192 + (size_t)b * 2048 + g0s * 8;

    bf16x8 qf[2][2];
#pragma unroll
    for (int mi = 0; mi < 2; ++mi)
#pragma unroll
        for (int kk = 0; kk < 2; ++kk)
            qf[mi][kk] = *(const bf16x8*)(Q + baseQ +
                (size_t)(q0 + w * 32 + mi * 16 + l15) * 1024 + kk * 32 + quad * 8);

    f32x4 accO[4][2];
    float l_part[2] = {0.f, 0.f};
#pragma unroll
    for (int nd = 0; nd < 4; ++nd)
#pragma unroll
        for (int mi = 0; mi < 2; ++mi) accO[nd][mi] = (f32x4){0.f, 0.f, 0.f, 0.f};

    auto swz = [&](int r, int g) { return (r * 8 + (g ^ (r & 7))) * 8; };
    auto stage = [&](int t0, int bi) {
        async16((bf16*)Ks[bi] + w * 512, gK0 + (size_t)t0 * 1024);
        async16((bf16*)Vs[bi] + w * 512, gV0 + t0);
    };

    stage(0, 0);

    for (int it = 0; it < 32; ++it) {
        __syncthreads();
        if (it + 1 < 32) stage((it + 1) * 64, (it + 1) & 1);
        const bf16* Kb = Ks[it & 1];
        const bf16* Vb = Vs[it & 1];

        f32x4 accS[4][2];
#pragma unroll
        for (int nt = 0; nt < 4; ++nt)
#pragma unroll
            for (int mi = 0; mi < 2; ++mi) accS[nt][mi] = (f32x4){0.f, 0.f, 0.f, 0.f};
#pragma unroll
        for (int kk = 0; kk < 2; ++kk) {
            bf16x8 kf[4];
#pragma unroll
            for (int nt = 0; nt < 4; ++nt)
                kf[nt] = *(const bf16x8*)&Kb[swz(nt * 16 + l15, kk * 4 + quad)];
            __builtin_amdgcn_s_setprio(1);
#pragma unroll
            for (int nt = 0; nt < 4; ++nt)
#pragma unroll
                for (int mi = 0; mi < 2; ++mi)
                    accS[nt][mi] = __builtin_amdgcn_mfma_f32_16x16x32_bf16(
                        kf[nt], qf[mi][kk], accS[nt][mi], 0, 0, 0);
            __builtin_amdgcn_s_setprio(0);
        }

        bf16* Pp = &Pt[w][0];
#pragma unroll
        for (int mi = 0; mi < 2; ++mi) {
            const int qbase = (mi * 16 + l15) * 64;
            float rs = 0.f;
#pragma unroll
            for (int nt = 0; nt < 4; ++nt) {
                bf16x4 pk;
#pragma unroll
                for (int r = 0; r < 4; ++r) {
                    float p = __builtin_amdgcn_exp2f(accS[nt][mi][r]);
                    rs += p;
                    pk[r] = (bf16)p;
                }
                *(bf16x4*)&Pp[qbase + (((nt * 2 + (quad >> 1)) ^ q7) * 8) +
                              (quad & 1) * 4] = pk;
            }
            l_part[mi] += rs;
        }

#pragma unroll
        for (int kk = 0; kk < 2; ++kk) {
            bf16x8 vf[4], pf[2];
#pragma unroll
            for (int nd = 0; nd < 4; ++nd)
                vf[nd] = *(const bf16x8*)&Vb[swz(nd * 16 + l15, kk * 4 + quad)];
#pragma unroll
            for (int mi = 0; mi < 2; ++mi)
                pf[mi] = *(const bf16x8*)&Pp[(mi * 16 + l15) * 64 +
                                             (((kk * 4 + quad) ^ q7) * 8)];
            __builtin_amdgcn_s_setprio(1);
#pragma unroll
            for (int nd = 0; nd < 4; ++nd)
#pragma unroll
                for (int mi = 0; mi < 2; ++mi)
                    accO[nd][mi] = __builtin_amdgcn_mfma_f32_16x16x32_bf16(
                        vf[nd], pf[mi], accO[nd][mi], 0, 0, 0);
            __builtin_amdgcn_s_setprio(0);
        }
    }

    float inv[2];
#pragma unroll
    for (int mi = 0; mi < 2; ++mi) {
        float l = l_part[mi];
        l += __shfl_xor(l, 16);
        l += __shfl_xor(l, 32);
        inv[mi] = 1.0f / l;
    }

#pragma unroll
    for (int mi = 0; mi < 2; ++mi) {
        size_t rowoff = baseQ + (size_t)(q0 + w * 32 + mi * 16 + l15) * 1024;
#pragma unroll
        for (int nd = 0; nd < 4; ++nd) {
            bf16x4 o;
#pragma unroll
            for (int r = 0; r < 4; ++r) o[r] = (bf16)(accO[nd][mi][r] * inv[mi]);
            *(bf16x4*)&O[rowoff + nd * 16 + quad * 4] = o;
        }
    }
}

// ---------------------------------------------------------------------------
extern "C" void kernel_launch(void* const* d_in, const int* in_sizes, int n_in,
                              void* d_out, int out_size, void* d_ws, size_t ws_size,
                              hipStream_t stream) {
    const float* qin = (const float*)d_in[0];
    const float* kin = (const float*)d_in[1];
    const float* vin = (const float*)d_in[2];
    const float* Wq = (const float*)d_in[3];
    const float* Wk = (const float*)d_in[4];
    const float* Wv = (const float*)d_in[5];
    const float* Wo = (const float*)d_in[6];
    float* out = (float*)d_out;

    char* ws = (char*)d_ws;
    bf16* Qb  = (bf16*)(ws + ((size_t)48 << 20));
    bf16* Kb  = (bf16*)(ws + ((size_t)64 << 20));
    bf16* VtG = (bf16*)(ws + ((size_t)80 << 20));  // [1024][8192] = V^T
    bf16* Cb  = (bf16*)(ws);                       // ctx buffer
    bf16* Wqt = (bf16*)(ws + ((size_t)96 << 20));
    bf16* Wkt = Wqt + 1024 * 1024;
    bf16* Wvt = Wkt + 1024 * 1024;
    bf16* Wot = Wvt + 1024 * 1024;

    prep<<<dim3(1024), 256, 0, stream>>>(Wq, Wk, Wv, Wo, Wqt, Wkt, Wvt, Wot);
    gemm_qkv<<<dim3(512, 1, 3), 256, 0, stream>>>(qin, kin, vin, Wqt, Wkt, Wvt,
                                                  Qb, Kb, VtG);
    attn_fa<<<dim3(512), 512, 0, stream>>>(Qb, Kb, VtG, Cb);
    gemm_out<<<dim3(512), 256, 0, stream>>>(Cb, Wot, out);
}

// Round 5
// 314.837 us; speedup vs baseline: 1.2375x; 1.1168x over previous
//
#include <hip/hip_runtime.h>
#include <stdint.h>

typedef __bf16 bf16;
typedef __bf16 bf16x4 __attribute__((ext_vector_type(4)));
typedef __bf16 bf16x8 __attribute__((ext_vector_type(8)));
typedef float f32x4 __attribute__((ext_vector_type(4)));
typedef float f32x16 __attribute__((ext_vector_type(16)));

#define AS1 __attribute__((address_space(1)))
#define AS3 __attribute__((address_space(3)))

__device__ __forceinline__ void async16(void* lds, const void* g) {
    __builtin_amdgcn_global_load_lds((AS1 void*)g, (AS3 void*)lds, 16, 0, 0);
}

// ---------------------------------------------------------------------------
// Prep: z<3 -> fp32->bf16 convert of X tensors; z==3 -> 4 weight transposes.
// ---------------------------------------------------------------------------
__global__ __launch_bounds__(256) void prep(
    const float* __restrict__ x0, const float* __restrict__ x1,
    const float* __restrict__ x2,
    bf16* __restrict__ y0, bf16* __restrict__ y1, bf16* __restrict__ y2,
    const float* __restrict__ s0, const float* __restrict__ s1,
    const float* __restrict__ s2, const float* __restrict__ s3,
    bf16* __restrict__ d0, bf16* __restrict__ d1,
    bf16* __restrict__ d2, bf16* __restrict__ d3) {
    const int z = blockIdx.z;
    const int t = threadIdx.x;
    if (z < 3) {
        const float* x = z == 0 ? x0 : z == 1 ? x1 : x2;
        bf16* y = z == 0 ? y0 : z == 1 ? y1 : y2;
        int i = (blockIdx.x * 256 + t) * 8;
        f32x4 a = *(const f32x4*)(x + i);
        f32x4 b = *(const f32x4*)(x + i + 4);
        bf16x8 o;
#pragma unroll
        for (int j = 0; j < 4; ++j) { o[j] = (bf16)a[j]; o[4 + j] = (bf16)b[j]; }
        *(bf16x8*)(y + i) = o;
        return;
    }
    const int bx = blockIdx.x;
    if (bx >= 1024) return;
    const int wsel = bx >> 8, tile = bx & 255;
    const float* W = wsel == 0 ? s0 : wsel == 1 ? s1 : wsel == 2 ? s2 : s3;
    bf16* Wt = wsel == 0 ? d0 : wsel == 1 ? d1 : wsel == 2 ? d2 : d3;
    const int k0 = (tile >> 4) * 64, n0 = (tile & 15) * 64;
    __shared__ float Ts[64 * 65];
    const int c = t & 63, r0 = t >> 6;
#pragma unroll
    for (int i = 0; i < 16; ++i) {
        int r = r0 + i * 4;
        Ts[r * 65 + c] = W[(size_t)(k0 + r) * 1024 + n0 + c];
    }
    __syncthreads();
#pragma unroll
    for (int i = 0; i < 16; ++i) {
        int r = r0 + i * 4;
        Wt[(size_t)(n0 + r) * 1024 + k0 + c] = (bf16)Ts[c * 65 + r];
    }
}

// ---------------------------------------------------------------------------
// 128x128 GEMM body, BK=64, xor-swizzled LDS rows (conflict-free b128 reads).
// C[M][N] = A[M][K]*Bt[N][K]^T * scale. 16 K-iterations at K=1024.
// (round-1 verified structure: global_load_lds staging, 2 barriers/iter)
// ---------------------------------------------------------------------------
template <typename OutT>
__device__ __forceinline__ void gemm_body(const bf16* __restrict__ A,
                                          const bf16* __restrict__ Bt,
                                          OutT* __restrict__ C,
                                          int N, int K, float scale,
                                          int m0, int n0,
                                          bf16* As, bf16* Bs) {
    const int t = threadIdx.x;
    const int lane = t & 63;
    const int w = t >> 6;
    const int l15 = lane & 15;
    const int quad = lane >> 4;
    const int wm = w >> 1, wn = w & 1;

    f32x4 acc[4][4];
#pragma unroll
    for (int i = 0; i < 4; ++i)
#pragma unroll
        for (int j = 0; j < 4; ++j) acc[i][j] = (f32x4){0.f, 0.f, 0.f, 0.f};

    const bf16* gA[4];
    const bf16* gB[4];
#pragma unroll
    for (int j = 0; j < 4; ++j) {
        int c = j * 256 + t;
        int row = c >> 3, g = (c & 7) ^ (row & 7);
        gA[j] = A + (size_t)(m0 + row) * K + g * 8;
        gB[j] = Bt + (size_t)(n0 + row) * K + g * 8;
    }

    for (int k0 = 0; k0 < K; k0 += 64) {
        __syncthreads();
#pragma unroll
        for (int j = 0; j < 4; ++j) {
            async16(As + (j * 256 + w * 64) * 8, gA[j] + k0);
            async16(Bs + (j * 256 + w * 64) * 8, gB[j] + k0);
        }
        __syncthreads();
#pragma unroll
        for (int kk = 0; kk < 2; ++kk) {
            bf16x8 af[4], bfv[4];
#pragma unroll
            for (int mi = 0; mi < 4; ++mi) {
                int r = wm * 64 + mi * 16 + l15;
                af[mi] = *(const bf16x8*)&As[r * 64 + (((kk * 4 + quad) ^ (r & 7)) * 8)];
            }
#pragma unroll
            for (int ni = 0; ni < 4; ++ni) {
                int r = wn * 64 + ni * 16 + l15;
                bfv[ni] = *(const bf16x8*)&Bs[r * 64 + (((kk * 4 + quad) ^ (r & 7)) * 8)];
            }
#pragma unroll
            for (int mi = 0; mi < 4; ++mi)
#pragma unroll
                for (int ni = 0; ni < 4; ++ni)
                    acc[mi][ni] = __builtin_amdgcn_mfma_f32_16x16x32_bf16(
                        af[mi], bfv[ni], acc[mi][ni], 0, 0, 0);
        }
    }

#pragma unroll
    for (int mi = 0; mi < 4; ++mi)
#pragma unroll
        for (int ni = 0; ni < 4; ++ni)
#pragma unroll
            for (int r = 0; r < 4; ++r) {
                int row = m0 + wm * 64 + mi * 16 + quad * 4 + r;
                int col = n0 + wn * 64 + ni * 16 + l15;
                C[(size_t)row * N + col] = (OutT)(acc[mi][ni][r] * scale);
            }
}

// Batched Q/K/V projection. z=0: Qb=Xq*Wq^T*(0.125*log2e); z=1: Kb; z=2: VtG.
__global__ __launch_bounds__(256) void gemm_qkv(
    const bf16* __restrict__ Xq, const bf16* __restrict__ Xk, const bf16* __restrict__ Xv,
    const bf16* __restrict__ Wqt, const bf16* __restrict__ Wkt, const bf16* __restrict__ Wvt,
    bf16* __restrict__ Qb, bf16* __restrict__ Kb, bf16* __restrict__ VtG) {
    __shared__ __align__(16) bf16 As[128 * 64];
    __shared__ __align__(16) bf16 Bs[128 * 64];
    const int z = blockIdx.z;
    const int blk = blockIdx.x;
    const int big  = (blk & 7) * 8 + (blk >> 6);  // 0..63, grouped 8-per-XCD
    const int sml  = (blk >> 3) & 7;              // 0..7
    const bf16* A; const bf16* Bt; bf16* C; int N; float scale; int m0, n0;
    if (z == 0) { A = Xq; Bt = Wqt; C = Qb; N = 1024; scale = 0.18033688011112042f;
                  m0 = big * 128; n0 = sml * 128; }   // 0.125 * log2(e)
    else if (z == 1) { A = Xk; Bt = Wkt; C = Kb; N = 1024; scale = 1.0f;
                  m0 = big * 128; n0 = sml * 128; }
    else { A = Wvt; Bt = Xv; C = VtG; N = 8192; scale = 1.0f;
                  m0 = sml * 128; n0 = big * 128; }
    gemm_body<bf16>(A, Bt, C, N, 1024, scale, m0, n0, As, Bs);
}

// Output projection: out[8192][1024] fp32 = Cb * Wot^T (same XCD grouping)
__global__ __launch_bounds__(256) void gemm_out(const bf16* __restrict__ A,
                                                const bf16* __restrict__ Bt,
                                                float* __restrict__ C) {
    __shared__ __align__(16) bf16 As[128 * 64];
    __shared__ __align__(16) bf16 Bs[128 * 64];
    const int blk = blockIdx.x;
    const int big = (blk & 7) * 8 + (blk >> 6);
    const int sml = (blk >> 3) & 7;
    gemm_body<float>(A, Bt, C, 1024, 1024, 1.0f, big * 128, sml * 128, As, Bs);
}

// ---------------------------------------------------------------------------
// Flash attention, 32x32x16 MFMA. S^T formulation, no online max
// (|s*log2e|<=10.7: fp32-safe). 4 waves x 64 q-rows = 256 q/block; 512
// blocks = 2 resident/CU (LDS exactly 64 KB). Each wave reads the K/V tile
// once per iter but produces 64 q (vs 32 before): per-q LDS traffic -33%.
// P kept in a wave-private swizzled [q][t] LDS buffer (no barrier).
// C/D layout 32x32: col=lane&31, row=(reg&3)+8*(reg>>2)+4*(lane>>5).
// A/B operand: row/col=lane&31, k=(lane>>5)*8+j.
// STAGING FIX vs round 4: global_load_lds LDS dest must be WAVE-UNIFORM
// (base + w*512 elements; HW scatters lane*16B). Per-lane swizzle lives in
// the pre-swizzled GLOBAL source pointers (m104/m108 rule).
// ---------------------------------------------------------------------------
__global__ __launch_bounds__(256, 2) void attn_fa(const bf16* __restrict__ Q,
                                                  const bf16* __restrict__ K,
                                                  const bf16* __restrict__ Vt,
                                                  bf16* __restrict__ O) {
    __shared__ __align__(16) bf16 Ks[2][64 * 64];   // swizzled [t][dh]
    __shared__ __align__(16) bf16 Vs[2][64 * 64];   // swizzled [dh][t]
    __shared__ __align__(16) bf16 Ps[4][64 * 64];   // per-wave P [q][t], swizzled

    const int t = threadIdx.x;
    const int lane = t & 63;
    const int w = t >> 6;
    const int l31 = lane & 31;
    const int h = lane >> 5;

    // bid&7 -> XCD; each XCD gets 8 (b,h) groups x 8 q-tiles (KV set = 4MB = L2)
    const int bid = blockIdx.x;
    const int bh = (bid & 7) * 8 + ((bid >> 3) & 7);
    const int q0 = (bid >> 6) * 256;
    const int b = bh >> 4, hh = bh & 15;
    const size_t baseQ = (size_t)b * 2048 * 1024 + (size_t)hh * 64;

    // staging chunk mapping (xor swizzle, 16B granular): chunks t and t+256
    const int r0s = t >> 3,          g0s = (t & 7) ^ (r0s & 7);
    const int r1s = (t + 256) >> 3,  g1s = ((t + 256) & 7) ^ (r1s & 7);
    const bf16* gK0 = K + baseQ + (size_t)r0s * 1024 + g0s * 8;
    const bf16* gK1 = K + baseQ + (size_t)r1s * 1024 + g1s * 8;
    const bf16* gV0 = Vt + (size_t)(hh * 64 + r0s) * 8192 + (size_t)b * 2048 + g0s * 8;
    const bf16* gV1 = Vt + (size_t)(hh * 64 + r1s) * 8192 + (size_t)b * 2048 + g1s * 8;

    // Q fragments (B-operand): qf[Qt][c]: q = q0+w*64+Qt*32+l31, dh = c*16+h*8..
    bf16x8 qf[2][4];
#pragma unroll
    for (int Qt = 0; Qt < 2; ++Qt)
#pragma unroll
        for (int c = 0; c < 4; ++c)
            qf[Qt][c] = *(const bf16x8*)(Q + baseQ +
                (size_t)(q0 + w * 64 + Qt * 32 + l31) * 1024 + c * 16 + h * 8);

    f32x16 accO[2][2];                // O^T tiles: [dh-tile][q-tile]
    float l_part[2] = {0.f, 0.f};
#pragma unroll
    for (int dt = 0; dt < 2; ++dt)
#pragma unroll
        for (int Qt = 0; Qt < 2; ++Qt)
#pragma unroll
            for (int r = 0; r < 16; ++r) accO[dt][Qt][r] = 0.f;

    // wave-uniform LDS dests; chunk c = w*64+lane -> element c*8 (lane*16B),
    // chunk 256+w*64+lane -> element 2048 + w*512 + lane*8.
    auto stage = [&](int t0, int bi) {
        async16((bf16*)Ks[bi] + w * 512,        gK0 + (size_t)t0 * 1024);
        async16((bf16*)Ks[bi] + 2048 + w * 512, gK1 + (size_t)t0 * 1024);
        async16((bf16*)Vs[bi] + w * 512,        gV0 + t0);
        async16((bf16*)Vs[bi] + 2048 + w * 512, gV1 + t0);
    };

    stage(0, 0);
    bf16* Pp = &Ps[w][0];

    for (int it = 0; it < 32; ++it) {
        __syncthreads();               // drains tile-it staging for all waves
        if (it + 1 < 32) stage((it + 1) * 64, (it + 1) & 1);
        const bf16* Kb = Ks[it & 1];
        const bf16* Vb = Vs[it & 1];

        // S^T = K_tile * Q^T : accS[T][Qt]; row t = T*32+(r&3)+8*(r>>2)+4h,
        // col q = Qt*32+l31
        f32x16 accS[2][2];
#pragma unroll
        for (int T = 0; T < 2; ++T)
#pragma unroll
            for (int Qt = 0; Qt < 2; ++Qt)
#pragma unroll
                for (int r = 0; r < 16; ++r) accS[T][Qt][r] = 0.f;
#pragma unroll
        for (int c = 0; c < 4; ++c) {
            bf16x8 kf[2];
#pragma unroll
            for (int T = 0; T < 2; ++T) {
                int tr = T * 32 + l31;
                kf[T] = *(const bf16x8*)&Kb[tr * 64 + (((c * 2 + h) ^ (tr & 7)) * 8)];
            }
            __builtin_amdgcn_s_setprio(1);
#pragma unroll
            for (int T = 0; T < 2; ++T)
#pragma unroll
                for (int Qt = 0; Qt < 2; ++Qt)
                    accS[T][Qt] = __builtin_amdgcn_mfma_f32_32x32x16_bf16(
                        kf[T], qf[Qt][c], accS[T][Qt], 0, 0, 0);
            __builtin_amdgcn_s_setprio(0);
        }

        // P = exp2(s') (log2e folded into Q proj); store P[q][t] wave-private,
        // 16B groups xor-swizzled by q&7; l partials per q-tile.
#pragma unroll
        for (int Qt = 0; Qt < 2; ++Qt) {
            const int ql = Qt * 32 + l31;
            const int qbase = ql * 64;
            float rs = 0.f;
#pragma unroll
            for (int T = 0; T < 2; ++T)
#pragma unroll
                for (int g = 0; g < 4; ++g) {
                    bf16x4 pk;
#pragma unroll
                    for (int o = 0; o < 4; ++o) {
                        float p = __builtin_amdgcn_exp2f(accS[T][Qt][g * 4 + o]);
                        rs += p;
                        pk[o] = (bf16)p;
                    }
                    int tg = T * 4 + g;   // t in [tg*8, tg*8+8), our half = h*4
                    *(bf16x4*)&Pp[qbase + ((tg ^ (ql & 7)) * 8) + h * 4] = pk;
                }
            l_part[Qt] += rs;
        }

        // O^T += V^T * P^T  (A = V^T frag from LDS, B = P frag from LDS)
#pragma unroll
        for (int c = 0; c < 4; ++c) {
            bf16x8 vf[2], pf[2];
#pragma unroll
            for (int dt = 0; dt < 2; ++dt) {
                int dh = dt * 32 + l31;
                vf[dt] = *(const bf16x8*)&Vb[dh * 64 + (((c * 2 + h) ^ (dh & 7)) * 8)];
            }
#pragma unroll
            for (int Qt = 0; Qt < 2; ++Qt) {
                int ql = Qt * 32 + l31;
                int tg = c * 2 + h;
                pf[Qt] = *(const bf16x8*)&Pp[ql * 64 + ((tg ^ (ql & 7)) * 8)];
            }
            __builtin_amdgcn_s_setprio(1);
#pragma unroll
            for (int dt = 0; dt < 2; ++dt)
#pragma unroll
                for (int Qt = 0; Qt < 2; ++Qt)
                    accO[dt][Qt] = __builtin_amdgcn_mfma_f32_32x32x16_bf16(
                        vf[dt], pf[Qt], accO[dt][Qt], 0, 0, 0);
            __builtin_amdgcn_s_setprio(0);
        }
    }

    // final l reduction: lane covers 32 t-values; partner (lane^32) the rest
    float inv[2];
#pragma unroll
    for (int Qt = 0; Qt < 2; ++Qt) {
        float l = l_part[Qt];
        l += __shfl_xor(l, 32);
        inv[Qt] = 1.0f / l;
    }

    // epilogue: ctx[q][hh*64+dh] = O^T[dh][q]/l ; dh = dt*32+g*8+h*4+o
#pragma unroll
    for (int Qt = 0; Qt < 2; ++Qt) {
        size_t rowoff = baseQ + (size_t)(q0 + w * 64 + Qt * 32 + l31) * 1024;
#pragma unroll
        for (int dt = 0; dt < 2; ++dt)
#pragma unroll
            for (int g = 0; g < 4; ++g) {
                bf16x4 o;
#pragma unroll
                for (int r = 0; r < 4; ++r)
                    o[r] = (bf16)(accO[dt][Qt][g * 4 + r] * inv[Qt]);
                *(bf16x4*)&O[rowoff + dt * 32 + g * 8 + h * 4] = o;
            }
    }
}

// ---------------------------------------------------------------------------
extern "C" void kernel_launch(void* const* d_in, const int* in_sizes, int n_in,
                              void* d_out, int out_size, void* d_ws, size_t ws_size,
                              hipStream_t stream) {
    const float* qin = (const float*)d_in[0];
    const float* kin = (const float*)d_in[1];
    const float* vin = (const float*)d_in[2];
    const float* Wq = (const float*)d_in[3];
    const float* Wk = (const float*)d_in[4];
    const float* Wv = (const float*)d_in[5];
    const float* Wo = (const float*)d_in[6];
    float* out = (float*)d_out;

    char* ws = (char*)d_ws;
    bf16* Xq  = (bf16*)(ws);                       // 16 MB each
    bf16* Xk  = (bf16*)(ws + ((size_t)16 << 20));
    bf16* Xv  = (bf16*)(ws + ((size_t)32 << 20));
    bf16* Qb  = (bf16*)(ws + ((size_t)48 << 20));
    bf16* Kb  = (bf16*)(ws + ((size_t)64 << 20));
    bf16* VtG = (bf16*)(ws + ((size_t)80 << 20));  // [1024][8192] = V^T
    bf16* Cb  = (bf16*)(ws);                       // alias Xq (dead after gemm_qkv)
    bf16* Wqt = (bf16*)(ws + ((size_t)96 << 20));
    bf16* Wkt = Wqt + 1024 * 1024;
    bf16* Wvt = Wkt + 1024 * 1024;
    bf16* Wot = Wvt + 1024 * 1024;

    prep<<<dim3(4096, 1, 4), 256, 0, stream>>>(qin, kin, vin, Xq, Xk, Xv,
                                               Wq, Wk, Wv, Wo, Wqt, Wkt, Wvt, Wot);
    gemm_qkv<<<dim3(512, 1, 3), 256, 0, stream>>>(Xq, Xk, Xv, Wqt, Wkt, Wvt,
                                                  Qb, Kb, VtG);
    attn_fa<<<dim3(512), 256, 0, stream>>>(Qb, Kb, VtG, Cb);
    gemm_out<<<dim3(512), 256, 0, stream>>>(Cb, Wot, out);
}